// Round 2
// baseline (4489.084 us; speedup 1.0000x reference)
//
#include <hip/hip_runtime.h>
#include <stdint.h>
#include <stddef.h>

// Problem constants
#define S_LEN 128
#define B_SZ  64
#define V_SZ  32000
#define EH    512
#define EO    512
#define H_SZ  1024
#define O_SZ  1024
#define G3    3072   // 3*H

typedef __attribute__((ext_vector_type(8))) short short8;
typedef __attribute__((ext_vector_type(4))) float floatx4;
typedef __attribute__((ext_vector_type(8))) unsigned short ushortx8;

__device__ __forceinline__ unsigned short f2bf(float f) {
  unsigned u = __builtin_bit_cast(unsigned, f);
  u += 0x7FFFu + ((u >> 16) & 1u);   // round-to-nearest-even
  return (unsigned short)(u >> 16);
}
__device__ __forceinline__ float bf2f(unsigned short h) {
  unsigned u = ((unsigned)h) << 16;
  return __builtin_bit_cast(float, u);
}

__device__ __forceinline__ void gld_lds16(const void* g, void* l) {
  __builtin_amdgcn_global_load_lds((const __attribute__((address_space(1))) void*)g,
                                   (__attribute__((address_space(3))) void*)l, 16, 0, 0);
}

// ---------------------------------------------------------------- converts
__global__ __launch_bounds__(256) void cvt_bf16(const float* __restrict__ in,
                                                unsigned short* __restrict__ out, int n4) {
  int i = blockIdx.x * 256 + threadIdx.x;
  if (i < n4) {
    float4 v = ((const float4*)in)[i];
    ushort4 o;
    o.x = f2bf(v.x); o.y = f2bf(v.y); o.z = f2bf(v.z); o.w = f2bf(v.w);
    ((ushort4*)out)[i] = o;
  }
}

// ------------------------------------------------- W1 [EH][V] -> W1T bf16 [V][EH]
__global__ __launch_bounds__(256) void transpose_w1_bf16(const float* __restrict__ W1,
                                                         unsigned short* __restrict__ W1T) {
  __shared__ unsigned short tile[64][72];   // [v][e], padded
  int t = threadIdx.x;
  int v0 = blockIdx.x * 64;
  int e0 = blockIdx.y * 64;
  for (int i = 0; i < 4; ++i) {
    int e = (t >> 4) + i * 16;
    int v = (t & 15) * 4;
    float4 w = *(const float4*)&W1[(size_t)(e0 + e) * V_SZ + v0 + v];
    tile[v + 0][e] = f2bf(w.x);
    tile[v + 1][e] = f2bf(w.y);
    tile[v + 2][e] = f2bf(w.z);
    tile[v + 3][e] = f2bf(w.w);
  }
  __syncthreads();
  for (int i = 0; i < 2; ++i) {
    int v = (t >> 3) + i * 32;
    int e = (t & 7) * 8;
    ushortx8 o;
    for (int j = 0; j < 8; ++j) o[j] = tile[v][e + j];
    *(ushortx8*)&W1T[(size_t)(v0 + v) * EH + e0 + e] = o;
  }
}

// ------------------------------------------------- gather + b1 + threshold -> emb bf16
__global__ __launch_bounds__(256) void gather_emb(const int* __restrict__ ids,
                                                  const unsigned short* __restrict__ W1T,
                                                  const float* __restrict__ b1,
                                                  unsigned short* __restrict__ emb) {
  int t = threadIdx.x;
  int tok = blockIdx.x * 4 + (t >> 6);
  int lane = t & 63;
  int id = ids[tok];
  ushortx8 w = *(const ushortx8*)&W1T[(size_t)id * EH + lane * 8];
  float4 blo = *(const float4*)&b1[lane * 8];
  float4 bhi = *(const float4*)&b1[lane * 8 + 4];
  float bv[8] = {blo.x, blo.y, blo.z, blo.w, bhi.x, bhi.y, bhi.z, bhi.w};
  ushortx8 o;
  for (int j = 0; j < 8; ++j) {
    float x = bf2f(w[j]) + bv[j];
    x = (x > 1e-6f) ? x : 0.0f;
    o[j] = f2bf(x);
  }
  *(ushortx8*)&emb[(size_t)tok * EH + lane * 8] = o;
}

// ------------------------------------------------- MFMA GEMM, C = act(A @ B^T + bias)
template <int ACT, int OUT_BF16>
__global__ __launch_bounds__(256) void gemm_bt(const unsigned short* __restrict__ A,
                                               const unsigned short* __restrict__ B,
                                               const float* __restrict__ bias,
                                               void* __restrict__ Cout,
                                               int M, int N, int K) {
  __shared__ unsigned short lA[128 * 32];
  __shared__ unsigned short lB[128 * 32];
  int t = threadIdx.x;
  int lane = t & 63;
  int wave = t >> 6;
  int bn = blockIdx.x, bm = blockIdx.y;
  int wm = (wave >> 1) * 64;
  int wn = (wave & 1) * 64;
  floatx4 acc[4][4] = {};

  int arow = t >> 2;
  int acol = (t & 3) * 8;

  int ga0 = bm * 128 + arow;       if (ga0 >= M) ga0 = M - 1;
  int ga1 = bm * 128 + arow + 64;  if (ga1 >= M) ga1 = M - 1;
  const unsigned short* a0 = A + (size_t)ga0 * K + acol;
  const unsigned short* a1 = A + (size_t)ga1 * K + acol;
  const unsigned short* b0 = B + (size_t)(bn * 128 + arow) * K + acol;
  const unsigned short* b1 = B + (size_t)(bn * 128 + arow + 64) * K + acol;
  unsigned short* lA0 = &lA[t * 8];
  unsigned short* lA1 = &lA[t * 8 + 64 * 32];
  unsigned short* lB0 = &lB[t * 8];
  unsigned short* lB1 = &lB[t * 8 + 64 * 32];

  for (int k0 = 0; k0 < K; k0 += 32) {
    __syncthreads();
    gld_lds16(a0 + k0, lA0);
    gld_lds16(a1 + k0, lA1);
    gld_lds16(b0 + k0, lB0);
    gld_lds16(b1 + k0, lB1);
    __syncthreads();
    short8 af[4], bfr[4];
    for (int i = 0; i < 4; ++i)
      af[i] = *(const short8*)&lA[(wm + i * 16 + (lane & 15)) * 32 + (lane >> 4) * 8];
    for (int j = 0; j < 4; ++j)
      bfr[j] = *(const short8*)&lB[(wn + j * 16 + (lane & 15)) * 32 + (lane >> 4) * 8];
    for (int i = 0; i < 4; ++i)
      for (int j = 0; j < 4; ++j)
        acc[i][j] = __builtin_amdgcn_mfma_f32_16x16x32_bf16(af[i], bfr[j], acc[i][j], 0, 0, 0);
  }

  int rowq = (lane >> 4) * 4;
  for (int j = 0; j < 4; ++j) {
    int col = bn * 128 + wn + j * 16 + (lane & 15);
    float bv = bias[col];
    for (int i = 0; i < 4; ++i) {
      int row0 = bm * 128 + wm + i * 16 + rowq;
      for (int r = 0; r < 4; ++r) {
        int row = row0 + r;
        if (row < M) {
          float v = acc[i][j][r] + bv;
          if (ACT) v = (v > 1e-6f) ? v : 0.0f;
          if (OUT_BF16) ((unsigned short*)Cout)[(size_t)row * N + col] = f2bf(v);
          else          ((float*)Cout)[(size_t)row * N + col] = v;
        }
      }
    }
  }
}

// ------------------------------------------------- W_hh fp32 [3H][H] -> Wprep bf16 in
// MFMA-B-fragment order: Wprep[((cg*96 + g*32 + t)*64 + lane)*8 + j]
//   = W_hh[g*H + cg*16 + (lane&15)][t*32 + (lane>>4)*8 + j]
// so gru_persist's global_load_lds is an identity copy and ds_reads are lane-consecutive.
__global__ __launch_bounds__(256) void prep_whh(const float* __restrict__ W_hh,
                                                unsigned short* __restrict__ Wprep) {
  int tid = blockIdx.x * 256 + threadIdx.x;   // 393216 total
  int lane = tid & 63;
  int c = tid >> 6;          // chunk 0..6143
  int cg = c / 96;
  int r  = c % 96;
  int g  = r >> 5;
  int t  = r & 31;
  int row = g * H_SZ + cg * 16 + (lane & 15);
  int k   = t * 32 + (lane >> 4) * 8;
  const float* src = &W_hh[(size_t)row * H_SZ + k];
  float4 v0 = *(const float4*)src;
  float4 v1 = *(const float4*)(src + 4);
  ushortx8 o;
  o[0] = f2bf(v0.x); o[1] = f2bf(v0.y); o[2] = f2bf(v0.z); o[3] = f2bf(v0.w);
  o[4] = f2bf(v1.x); o[5] = f2bf(v1.y); o[6] = f2bf(v1.z); o[7] = f2bf(v1.w);
  ((ushortx8*)Wprep)[tid] = o;
}

// ------------------------------------------------- persistent GRU recurrence
// 256 blocks x 256 threads, cooperative. Block (bg,cg): batches [bg*16,+16),
// h-cols [cg*16,+16), all 3 gates. Wave w handles K-quarter [w*256,+256).
// W_hh slice LDS-resident across all 128 steps; h exchanged via global hprep
// buffers (A-fragment layout, double-buffered); fp32 master h in LDS.
__global__ __launch_bounds__(256) void gru_persist(const unsigned short* __restrict__ hprep0,
                                                   unsigned short* __restrict__ hprep1,
                                                   unsigned short* __restrict__ hbfinal,
                                                   const unsigned short* __restrict__ Wprep,
                                                   const float* __restrict__ b_hh,
                                                   const unsigned short* __restrict__ xW,
                                                   unsigned* __restrict__ bar) {
  __shared__ unsigned short lB[96 * 512];   // 98304 B : W_hh slice, fragment order
  __shared__ float lgh[3][4][256];          // 12288 B : per-wave K-partials
  __shared__ float lhf[256];                //  1024 B : fp32 master h slice
  int t = threadIdx.x;
  int lane = t & 63;
  int w = t >> 6;
  int bg = blockIdx.x >> 6;    // 0..3
  int cg = blockIdx.x & 63;    // 0..63

  // stage W_hh slice once (identity copy, 98 KB)
  const unsigned short* wsrc = Wprep + (size_t)cg * 96 * 512;
  for (int i = 0; i < 24; ++i) {
    int c = w * 24 + i;
    gld_lds16(wsrc + (size_t)c * 512 + lane * 8, &lB[c * 512 + lane * 8]);
  }
  lhf[t] = 0.0f;

  // per-thread update-element constants
  int b_loc = t >> 4;
  int j_loc = t & 15;
  int jcol = cg * 16 + j_loc;          // h column
  int bglob = bg * 16 + b_loc;         // batch
  float bhr = b_hh[jcol];
  float bhz = b_hh[H_SZ + jcol];
  float bhn = b_hh[2 * H_SZ + jcol];
  // scatter-store position for h_new (A-fragment layout)
  int tt2 = jcol >> 5;
  int q   = (jcol >> 3) & 3;
  int jj  = jcol & 7;
  int Ls  = b_loc | (q << 4);
  size_t hw_off = ((size_t)(bg * 32 + tt2) * 64 + Ls) * 8 + jj;

  const unsigned short* hbufs[2] = {hprep0, hprep1};
  __syncthreads();   // drains staging vmcnt

  for (int s = 0; s < S_LEN; ++s) {
    const unsigned short* hr = hbufs[s & 1];
    unsigned short* hw = (unsigned short*)hbufs[(s + 1) & 1];

    // A-fragments for my K-quarter (32 VGPRs), coalesced 16B/lane
    short8 a[8];
#pragma unroll
    for (int i = 0; i < 8; ++i) {
      int tt = w * 8 + i;
      a[i] = *(const short8*)(hr + ((size_t)(bg * 32 + tt) * 64 + lane) * 8);
    }
    // xw prefetch (independent of h)
    const unsigned short* xs = xW + (size_t)s * B_SZ * G3 + (size_t)bglob * G3;
    float xr = bf2f(xs[jcol]);
    float xz = bf2f(xs[H_SZ + jcol]);
    float xn = bf2f(xs[2 * H_SZ + jcol]);

    floatx4 acc[3] = {};
#pragma unroll
    for (int i = 0; i < 8; ++i) {
      int tt = w * 8 + i;
#pragma unroll
      for (int g = 0; g < 3; ++g) {
        short8 bfr = *(const short8*)&lB[((g * 32 + tt) * 64 + lane) * 8];
        acc[g] = __builtin_amdgcn_mfma_f32_16x16x32_bf16(a[i], bfr, acc[g], 0, 0, 0);
      }
    }
#pragma unroll
    for (int g = 0; g < 3; ++g)
#pragma unroll
      for (int r = 0; r < 4; ++r)
        lgh[g][w][((lane >> 4) * 4 + r) * 16 + (lane & 15)] = acc[g][r];
    __syncthreads();

    // gate update for my element (sum 4 K-partials)
    float ghr = lgh[0][0][t] + lgh[0][1][t] + lgh[0][2][t] + lgh[0][3][t] + bhr;
    float ghz = lgh[1][0][t] + lgh[1][1][t] + lgh[1][2][t] + lgh[1][3][t] + bhz;
    float ghn = lgh[2][0][t] + lgh[2][1][t] + lgh[2][2][t] + lgh[2][3][t] + bhn;
    float rr = 1.0f / (1.0f + __expf(-(xr + ghr)));
    float zz = 1.0f / (1.0f + __expf(-(xz + ghz)));
    float nn = tanhf(xn + rr * ghn);
    float ho = lhf[t];
    float hnew = (1.0f - zz) * nn + zz * ho;
    lhf[t] = hnew;
    hw[hw_off] = f2bf(hnew);
    if (s == S_LEN - 1) hbfinal[(size_t)bglob * H_SZ + jcol] = f2bf(hnew);

    if (s < S_LEN - 1) {
      __threadfence();          // release: make h stores visible device-wide
      __syncthreads();          // all block threads' stores ordered before arrive
      if (t == 0) {
        __hip_atomic_fetch_add(bar, 1u, __ATOMIC_RELAXED, __HIP_MEMORY_SCOPE_AGENT);
        unsigned target = 256u * (unsigned)(s + 1);
        while (__hip_atomic_load(bar, __ATOMIC_RELAXED, __HIP_MEMORY_SCOPE_AGENT) < target)
          __builtin_amdgcn_s_sleep(2);
        __threadfence();        // acquire: invalidate stale L1/L2 before consuming
      }
      __syncthreads();
    }
  }
}

// ----------------------------------------------------------------- launch
extern "C" void kernel_launch(void* const* d_in, const int* in_sizes, int n_in,
                              void* d_out, int out_size, void* d_ws, size_t ws_size,
                              hipStream_t stream) {
  const int*   ids   = (const int*)d_in[0];
  const float* W1    = (const float*)d_in[1];
  const float* b1    = (const float*)d_in[2];
  const float* W2    = (const float*)d_in[3];
  const float* b2    = (const float*)d_in[4];
  const float* W_ih  = (const float*)d_in[5];
  const float* b_ih  = (const float*)d_in[6];
  const float* W_hh  = (const float*)d_in[7];
  const float* b_hh  = (const float*)d_in[8];
  const float* W_out = (const float*)d_in[9];
  const float* b_out = (const float*)d_in[10];
  float* out = (float*)d_out;

  uint8_t* wsp = (uint8_t*)d_ws;
  auto alloc = [&](size_t bytes) {
    uint8_t* p = wsp;
    wsp += (bytes + 255) & ~(size_t)255;
    return p;
  };
  unsigned short* W1T   = (unsigned short*)alloc((size_t)V_SZ * EH * 2);
  unsigned short* W2b   = (unsigned short*)alloc((size_t)EO * EH * 2);
  unsigned short* Wihb  = (unsigned short*)alloc((size_t)G3 * EO * 2);
  unsigned short* Wprep = (unsigned short*)alloc((size_t)G3 * H_SZ * 2);
  unsigned short* Woutb = (unsigned short*)alloc((size_t)O_SZ * H_SZ * 2);
  unsigned short* emb   = (unsigned short*)alloc((size_t)S_LEN * B_SZ * EH * 2);
  unsigned short* x     = (unsigned short*)alloc((size_t)S_LEN * B_SZ * EO * 2);
  unsigned short* xW    = (unsigned short*)alloc((size_t)S_LEN * B_SZ * G3 * 2);
  unsigned short* hprep0 = (unsigned short*)alloc((size_t)B_SZ * H_SZ * 2);
  unsigned short* hprep1 = (unsigned short*)alloc((size_t)B_SZ * H_SZ * 2);
  unsigned short* hbfinal = (unsigned short*)alloc((size_t)B_SZ * H_SZ * 2);
  unsigned*       bar     = (unsigned*)alloc(256);

  // weight converts (fp32 -> bf16)
  {
    int n4;
    n4 = (EO * EH) / 4;
    cvt_bf16<<<dim3((n4 + 255) / 256), 256, 0, stream>>>(W2, W2b, n4);
    n4 = (G3 * EO) / 4;
    cvt_bf16<<<dim3((n4 + 255) / 256), 256, 0, stream>>>(W_ih, Wihb, n4);
    n4 = (O_SZ * H_SZ) / 4;
    cvt_bf16<<<dim3((n4 + 255) / 256), 256, 0, stream>>>(W_out, Woutb, n4);
  }
  // W_hh -> MFMA-fragment-ordered bf16
  prep_whh<<<dim3(1536), 256, 0, stream>>>(W_hh, Wprep);

  // zero h0 (fragment-layout buffer read at s=0) and the grid barrier counter
  hipMemsetAsync(hprep0, 0, (size_t)B_SZ * H_SZ * 2, stream);
  hipMemsetAsync(bar, 0, 256, stream);

  // W1 transpose -> bf16
  transpose_w1_bf16<<<dim3(V_SZ / 64, EH / 64), 256, 0, stream>>>(W1, W1T);

  // embedding gather + b1 + threshold
  gather_emb<<<dim3(S_LEN * B_SZ / 4), 256, 0, stream>>>(ids, W1T, b1, emb);

  // x = thresh(emb @ W2^T + b2)
  gemm_bt<1, 1><<<dim3(EO / 128, S_LEN * B_SZ / 128), 256, 0, stream>>>(
      emb, W2b, b2, x, S_LEN * B_SZ, EO, EH);

  // xW = x @ W_ih^T + b_ih
  gemm_bt<0, 1><<<dim3(G3 / 128, S_LEN * B_SZ / 128), 256, 0, stream>>>(
      x, Wihb, b_ih, xW, S_LEN * B_SZ, G3, EO);

  // persistent GRU recurrence (cooperative: all 256 blocks co-resident)
  {
    void* args[] = {(void*)&hprep0, (void*)&hprep1, (void*)&hbfinal,
                    (void*)&Wprep, (void*)&b_hh, (void*)&xW, (void*)&bar};
    hipLaunchCooperativeKernel((const void*)gru_persist, dim3(256), dim3(256),
                               args, 0, stream);
  }

  // out = h @ W_out^T + b_out
  gemm_bt<0, 0><<<dim3(O_SZ / 128, 1), 256, 0, stream>>>(
      hbfinal, Woutb, b_out, out, B_SZ, O_SZ, H_SZ);
}

// Round 3
// 670.663 us; speedup vs baseline: 6.6935x; 6.6935x over previous
//
#include <hip/hip_runtime.h>
#include <stdint.h>
#include <stddef.h>

// Problem constants
#define S_LEN 128
#define B_SZ  64
#define V_SZ  32000
#define EH    512
#define EO    512
#define H_SZ  1024
#define O_SZ  1024
#define G3    3072   // 3*H

typedef __attribute__((ext_vector_type(8))) short short8;
typedef __attribute__((ext_vector_type(4))) float floatx4;
typedef __attribute__((ext_vector_type(8))) unsigned short ushortx8;
typedef __attribute__((ext_vector_type(4))) unsigned uintx4;

__device__ __forceinline__ unsigned short f2bf(float f) {
  unsigned u = __builtin_bit_cast(unsigned, f);
  u += 0x7FFFu + ((u >> 16) & 1u);   // round-to-nearest-even
  return (unsigned short)(u >> 16);
}
__device__ __forceinline__ float bf2f(unsigned short h) {
  unsigned u = ((unsigned)h) << 16;
  return __builtin_bit_cast(float, u);
}

__device__ __forceinline__ void gld_lds16(const void* g, void* l) {
  __builtin_amdgcn_global_load_lds((const __attribute__((address_space(1))) void*)g,
                                   (__attribute__((address_space(3))) void*)l, 16, 0, 0);
}

// ---------------------------------------------------------------- converts
__global__ __launch_bounds__(256) void cvt_bf16(const float* __restrict__ in,
                                                unsigned short* __restrict__ out, int n4) {
  int i = blockIdx.x * 256 + threadIdx.x;
  if (i < n4) {
    float4 v = ((const float4*)in)[i];
    ushort4 o;
    o.x = f2bf(v.x); o.y = f2bf(v.y); o.z = f2bf(v.z); o.w = f2bf(v.w);
    ((ushort4*)out)[i] = o;
  }
}

// ------------------------------------------------- W1 [EH][V] -> W1T bf16 [V][EH]
__global__ __launch_bounds__(256) void transpose_w1_bf16(const float* __restrict__ W1,
                                                         unsigned short* __restrict__ W1T) {
  __shared__ unsigned short tile[64][72];   // [v][e], padded
  int t = threadIdx.x;
  int v0 = blockIdx.x * 64;
  int e0 = blockIdx.y * 64;
  for (int i = 0; i < 4; ++i) {
    int e = (t >> 4) + i * 16;
    int v = (t & 15) * 4;
    float4 w = *(const float4*)&W1[(size_t)(e0 + e) * V_SZ + v0 + v];
    tile[v + 0][e] = f2bf(w.x);
    tile[v + 1][e] = f2bf(w.y);
    tile[v + 2][e] = f2bf(w.z);
    tile[v + 3][e] = f2bf(w.w);
  }
  __syncthreads();
  for (int i = 0; i < 2; ++i) {
    int v = (t >> 3) + i * 32;
    int e = (t & 7) * 8;
    ushortx8 o;
    for (int j = 0; j < 8; ++j) o[j] = tile[v][e + j];
    *(ushortx8*)&W1T[(size_t)(v0 + v) * EH + e0 + e] = o;
  }
}

// ------------------------------------------------- gather + b1 + threshold -> emb bf16
__global__ __launch_bounds__(256) void gather_emb(const int* __restrict__ ids,
                                                  const unsigned short* __restrict__ W1T,
                                                  const float* __restrict__ b1,
                                                  unsigned short* __restrict__ emb) {
  int t = threadIdx.x;
  int tok = blockIdx.x * 4 + (t >> 6);
  int lane = t & 63;
  int id = ids[tok];
  ushortx8 w = *(const ushortx8*)&W1T[(size_t)id * EH + lane * 8];
  float4 blo = *(const float4*)&b1[lane * 8];
  float4 bhi = *(const float4*)&b1[lane * 8 + 4];
  float bv[8] = {blo.x, blo.y, blo.z, blo.w, bhi.x, bhi.y, bhi.z, bhi.w};
  ushortx8 o;
  for (int j = 0; j < 8; ++j) {
    float x = bf2f(w[j]) + bv[j];
    x = (x > 1e-6f) ? x : 0.0f;
    o[j] = f2bf(x);
  }
  *(ushortx8*)&emb[(size_t)tok * EH + lane * 8] = o;
}

// ------------------------------------------------- MFMA GEMM, C = act(A @ B^T + bias)
template <int ACT, int OUT_BF16>
__global__ __launch_bounds__(256) void gemm_bt(const unsigned short* __restrict__ A,
                                               const unsigned short* __restrict__ B,
                                               const float* __restrict__ bias,
                                               void* __restrict__ Cout,
                                               int M, int N, int K) {
  __shared__ unsigned short lA[128 * 32];
  __shared__ unsigned short lB[128 * 32];
  int t = threadIdx.x;
  int lane = t & 63;
  int wave = t >> 6;
  int bn = blockIdx.x, bm = blockIdx.y;
  int wm = (wave >> 1) * 64;
  int wn = (wave & 1) * 64;
  floatx4 acc[4][4] = {};

  int arow = t >> 2;
  int acol = (t & 3) * 8;

  int ga0 = bm * 128 + arow;       if (ga0 >= M) ga0 = M - 1;
  int ga1 = bm * 128 + arow + 64;  if (ga1 >= M) ga1 = M - 1;
  const unsigned short* a0 = A + (size_t)ga0 * K + acol;
  const unsigned short* a1 = A + (size_t)ga1 * K + acol;
  const unsigned short* b0 = B + (size_t)(bn * 128 + arow) * K + acol;
  const unsigned short* b1 = B + (size_t)(bn * 128 + arow + 64) * K + acol;
  unsigned short* lA0 = &lA[t * 8];
  unsigned short* lA1 = &lA[t * 8 + 64 * 32];
  unsigned short* lB0 = &lB[t * 8];
  unsigned short* lB1 = &lB[t * 8 + 64 * 32];

  for (int k0 = 0; k0 < K; k0 += 32) {
    __syncthreads();
    gld_lds16(a0 + k0, lA0);
    gld_lds16(a1 + k0, lA1);
    gld_lds16(b0 + k0, lB0);
    gld_lds16(b1 + k0, lB1);
    __syncthreads();
    short8 af[4], bfr[4];
    for (int i = 0; i < 4; ++i)
      af[i] = *(const short8*)&lA[(wm + i * 16 + (lane & 15)) * 32 + (lane >> 4) * 8];
    for (int j = 0; j < 4; ++j)
      bfr[j] = *(const short8*)&lB[(wn + j * 16 + (lane & 15)) * 32 + (lane >> 4) * 8];
    for (int i = 0; i < 4; ++i)
      for (int j = 0; j < 4; ++j)
        acc[i][j] = __builtin_amdgcn_mfma_f32_16x16x32_bf16(af[i], bfr[j], acc[i][j], 0, 0, 0);
  }

  int rowq = (lane >> 4) * 4;
  for (int j = 0; j < 4; ++j) {
    int col = bn * 128 + wn + j * 16 + (lane & 15);
    float bv = bias[col];
    for (int i = 0; i < 4; ++i) {
      int row0 = bm * 128 + wm + i * 16 + rowq;
      for (int r = 0; r < 4; ++r) {
        int row = row0 + r;
        if (row < M) {
          float v = acc[i][j][r] + bv;
          if (ACT) v = (v > 1e-6f) ? v : 0.0f;
          if (OUT_BF16) ((unsigned short*)Cout)[(size_t)row * N + col] = f2bf(v);
          else          ((float*)Cout)[(size_t)row * N + col] = v;
        }
      }
    }
  }
}

// ------------------------------------------------- W_hh fp32 [3H][H] -> Wprep bf16 in
// MFMA-B-fragment order (see gru_persist).
__global__ __launch_bounds__(256) void prep_whh(const float* __restrict__ W_hh,
                                                unsigned short* __restrict__ Wprep) {
  int tid = blockIdx.x * 256 + threadIdx.x;   // 393216 total
  int lane = tid & 63;
  int c = tid >> 6;          // chunk 0..6143
  int cg = c / 96;
  int r  = c % 96;
  int g  = r >> 5;
  int t  = r & 31;
  int row = g * H_SZ + cg * 16 + (lane & 15);
  int k   = t * 32 + (lane >> 4) * 8;
  const float* src = &W_hh[(size_t)row * H_SZ + k];
  float4 v0 = *(const float4*)src;
  float4 v1 = *(const float4*)(src + 4);
  ushortx8 o;
  o[0] = f2bf(v0.x); o[1] = f2bf(v0.y); o[2] = f2bf(v0.z); o[3] = f2bf(v0.w);
  o[4] = f2bf(v1.x); o[5] = f2bf(v1.y); o[6] = f2bf(v1.z); o[7] = f2bf(v1.w);
  ((ushortx8*)Wprep)[tid] = o;
}

// ------------------------------------------------- persistent GRU recurrence
// 256 blocks x 256 threads, cooperative. Block (bg,cg): batches [bg*16,+16),
// h-cols [cg*16,+16), all 3 gates; wave w = K-quarter [w*256,+256).
// FENCE-FREE cross-block coherence: h exchanged through the coherence point
// with sc1 accesses (agent-scope relaxed atomics / inline-asm sc1 loads).
// No __threadfence -> no buffer_wbl2/buffer_inv L2 walks (round-2's 30us/step).
// Barrier: per-bg monotonic counter (only the 64 blocks sharing a batch group
// need to sync); __syncthreads drains vmcnt before the arrive-add.
__global__ __launch_bounds__(256) void gru_persist(const unsigned short* __restrict__ hprep0,
                                                   unsigned short* __restrict__ hprep1,
                                                   unsigned short* __restrict__ hbfinal,
                                                   const unsigned short* __restrict__ Wprep,
                                                   const float* __restrict__ b_hh,
                                                   const unsigned short* __restrict__ xW,
                                                   unsigned* __restrict__ bar) {
  __shared__ unsigned short lB[96 * 512];   // 98304 B : W_hh slice, fragment order
  __shared__ float lgh[3][4][256];          // 12288 B : per-wave K-partials
  __shared__ float lhf[256];                //  1024 B : fp32 master h slice
  int t = threadIdx.x;
  int lane = t & 63;
  int w = t >> 6;
  int bg = blockIdx.x >> 6;    // 0..3
  int cg = blockIdx.x & 63;    // 0..63

  // stage W_hh slice once (identity copy, 98 KB)
  const unsigned short* wsrc = Wprep + (size_t)cg * 96 * 512;
  for (int i = 0; i < 24; ++i) {
    int c = w * 24 + i;
    gld_lds16(wsrc + (size_t)c * 512 + lane * 8, &lB[c * 512 + lane * 8]);
  }
  lhf[t] = 0.0f;

  // per-thread update-element constants
  int b_loc = t >> 4;
  int j_loc = t & 15;
  int jcol = cg * 16 + j_loc;          // h column
  int bglob = bg * 16 + b_loc;         // batch
  float bhr = b_hh[jcol];
  float bhz = b_hh[H_SZ + jcol];
  float bhn = b_hh[2 * H_SZ + jcol];
  // scatter-store position for h_new (A-fragment layout); lane pairs (jj even/odd)
  // pack 2 bf16 into one dword store.
  int tt2 = jcol >> 5;
  int q   = (jcol >> 3) & 3;
  int jj  = jcol & 7;
  int Ls  = b_loc | (q << 4);
  size_t hw_off32 = ((((size_t)(bg * 32 + tt2) * 64 + Ls) * 8) + (jj & ~1)) >> 1;

  const unsigned short* hbufs[2] = {hprep0, hprep1};
  unsigned* barp = bar + bg * 64;      // per-bg counter, 256 B apart
  __syncthreads();   // drains staging vmcnt

  for (int s = 0; s < S_LEN; ++s) {
    const unsigned short* hr = hbufs[s & 1];
    unsigned* hw32 = (unsigned*)hbufs[(s + 1) & 1];

    // A-fragments for my K-quarter: 8 x 16B coherent (sc1) loads, pipelined,
    // one tied waitcnt. Bypasses stale L1/L2 without any cache-wide inv.
    uintx4 av[8];
#pragma unroll
    for (int i = 0; i < 8; ++i) {
      int tt = w * 8 + i;
      const void* ap = hr + ((size_t)(bg * 32 + tt) * 64 + lane) * 8;
      asm volatile("global_load_dwordx4 %0, %1, off sc1" : "=v"(av[i]) : "v"(ap));
    }
    // xw loads (plain cached; produced before kernel launch)
    const unsigned short* xs = xW + (size_t)s * B_SZ * G3 + (size_t)bglob * G3;
    float xr = bf2f(xs[jcol]);
    float xz = bf2f(xs[H_SZ + jcol]);
    float xn = bf2f(xs[2 * H_SZ + jcol]);
    asm volatile("s_waitcnt vmcnt(0)"
                 : "+v"(av[0]), "+v"(av[1]), "+v"(av[2]), "+v"(av[3]),
                   "+v"(av[4]), "+v"(av[5]), "+v"(av[6]), "+v"(av[7])
                 :: "memory");

    floatx4 acc[3] = {};
#pragma unroll
    for (int i = 0; i < 8; ++i) {
      int tt = w * 8 + i;
      short8 a = __builtin_bit_cast(short8, av[i]);
#pragma unroll
      for (int g = 0; g < 3; ++g) {
        short8 bfr = *(const short8*)&lB[((g * 32 + tt) * 64 + lane) * 8];
        acc[g] = __builtin_amdgcn_mfma_f32_16x16x32_bf16(a, bfr, acc[g], 0, 0, 0);
      }
    }
#pragma unroll
    for (int g = 0; g < 3; ++g)
#pragma unroll
      for (int r = 0; r < 4; ++r)
        lgh[g][w][((lane >> 4) * 4 + r) * 16 + (lane & 15)] = acc[g][r];
    __syncthreads();

    // gate update for my element (sum 4 K-partials)
    float ghr = lgh[0][0][t] + lgh[0][1][t] + lgh[0][2][t] + lgh[0][3][t] + bhr;
    float ghz = lgh[1][0][t] + lgh[1][1][t] + lgh[1][2][t] + lgh[1][3][t] + bhz;
    float ghn = lgh[2][0][t] + lgh[2][1][t] + lgh[2][2][t] + lgh[2][3][t] + bhn;
    float rr = 1.0f / (1.0f + __expf(-(xr + ghr)));
    float zz = 1.0f / (1.0f + __expf(-(xz + ghz)));
    float nn = tanhf(xn + rr * ghn);
    float ho = lhf[t];
    float hnew = (1.0f - zz) * nn + zz * ho;
    lhf[t] = hnew;

    unsigned hb = (unsigned)f2bf(hnew);
    unsigned other = (unsigned)__shfl_xor((int)hb, 1);
    if ((jj & 1) == 0) {
      unsigned packed = hb | (other << 16);   // (jj, jj+1)
      __hip_atomic_store(hw32 + hw_off32, packed,
                         __ATOMIC_RELAXED, __HIP_MEMORY_SCOPE_AGENT);
    }
    if (s == S_LEN - 1) hbfinal[(size_t)bglob * H_SZ + jcol] = (unsigned short)hb;

    if (s < S_LEN - 1) {
      __syncthreads();   // waitcnt vmcnt(0) + barrier: all block h-stores at L3
      if (t == 0) {
        __hip_atomic_fetch_add(barp, 1u, __ATOMIC_RELAXED, __HIP_MEMORY_SCOPE_AGENT);
        unsigned target = 64u * (unsigned)(s + 1);
        while (__hip_atomic_load(barp, __ATOMIC_RELAXED, __HIP_MEMORY_SCOPE_AGENT) < target)
          __builtin_amdgcn_s_sleep(2);
      }
      __syncthreads();
    }
  }
}

// ----------------------------------------------------------------- launch
extern "C" void kernel_launch(void* const* d_in, const int* in_sizes, int n_in,
                              void* d_out, int out_size, void* d_ws, size_t ws_size,
                              hipStream_t stream) {
  const int*   ids   = (const int*)d_in[0];
  const float* W1    = (const float*)d_in[1];
  const float* b1    = (const float*)d_in[2];
  const float* W2    = (const float*)d_in[3];
  const float* b2    = (const float*)d_in[4];
  const float* W_ih  = (const float*)d_in[5];
  const float* b_ih  = (const float*)d_in[6];
  const float* W_hh  = (const float*)d_in[7];
  const float* b_hh  = (const float*)d_in[8];
  const float* W_out = (const float*)d_in[9];
  const float* b_out = (const float*)d_in[10];
  float* out = (float*)d_out;

  uint8_t* wsp = (uint8_t*)d_ws;
  auto alloc = [&](size_t bytes) {
    uint8_t* p = wsp;
    wsp += (bytes + 255) & ~(size_t)255;
    return p;
  };
  unsigned short* W1T   = (unsigned short*)alloc((size_t)V_SZ * EH * 2);
  unsigned short* W2b   = (unsigned short*)alloc((size_t)EO * EH * 2);
  unsigned short* Wihb  = (unsigned short*)alloc((size_t)G3 * EO * 2);
  unsigned short* Wprep = (unsigned short*)alloc((size_t)G3 * H_SZ * 2);
  unsigned short* Woutb = (unsigned short*)alloc((size_t)O_SZ * H_SZ * 2);
  unsigned short* emb   = (unsigned short*)alloc((size_t)S_LEN * B_SZ * EH * 2);
  unsigned short* x     = (unsigned short*)alloc((size_t)S_LEN * B_SZ * EO * 2);
  unsigned short* xW    = (unsigned short*)alloc((size_t)S_LEN * B_SZ * G3 * 2);
  unsigned short* hprep0 = (unsigned short*)alloc((size_t)B_SZ * H_SZ * 2);
  unsigned short* hprep1 = (unsigned short*)alloc((size_t)B_SZ * H_SZ * 2);
  unsigned short* hbfinal = (unsigned short*)alloc((size_t)B_SZ * H_SZ * 2);
  unsigned*       bar     = (unsigned*)alloc(1024);

  // weight converts (fp32 -> bf16)
  {
    int n4;
    n4 = (EO * EH) / 4;
    cvt_bf16<<<dim3((n4 + 255) / 256), 256, 0, stream>>>(W2, W2b, n4);
    n4 = (G3 * EO) / 4;
    cvt_bf16<<<dim3((n4 + 255) / 256), 256, 0, stream>>>(W_ih, Wihb, n4);
    n4 = (O_SZ * H_SZ) / 4;
    cvt_bf16<<<dim3((n4 + 255) / 256), 256, 0, stream>>>(W_out, Woutb, n4);
  }
  // W_hh -> MFMA-fragment-ordered bf16
  prep_whh<<<dim3(1536), 256, 0, stream>>>(W_hh, Wprep);

  // zero h0 (fragment-layout buffer read at s=0) and the 4 barrier counters
  hipMemsetAsync(hprep0, 0, (size_t)B_SZ * H_SZ * 2, stream);
  hipMemsetAsync(bar, 0, 1024, stream);

  // W1 transpose -> bf16
  transpose_w1_bf16<<<dim3(V_SZ / 64, EH / 64), 256, 0, stream>>>(W1, W1T);

  // embedding gather + b1 + threshold
  gather_emb<<<dim3(S_LEN * B_SZ / 4), 256, 0, stream>>>(ids, W1T, b1, emb);

  // x = thresh(emb @ W2^T + b2)
  gemm_bt<1, 1><<<dim3(EO / 128, S_LEN * B_SZ / 128), 256, 0, stream>>>(
      emb, W2b, b2, x, S_LEN * B_SZ, EO, EH);

  // xW = x @ W_ih^T + b_ih
  gemm_bt<0, 1><<<dim3(G3 / 128, S_LEN * B_SZ / 128), 256, 0, stream>>>(
      x, Wihb, b_ih, xW, S_LEN * B_SZ, G3, EO);

  // persistent GRU recurrence (cooperative: all 256 blocks co-resident)
  {
    void* args[] = {(void*)&hprep0, (void*)&hprep1, (void*)&hbfinal,
                    (void*)&Wprep, (void*)&b_hh, (void*)&xW, (void*)&bar};
    hipLaunchCooperativeKernel((const void*)gru_persist, dim3(256), dim3(256),
                               args, 0, stream);
  }

  // out = h @ W_out^T + b_out
  gemm_bt<0, 0><<<dim3(O_SZ / 128, 1), 256, 0, stream>>>(
      hbfinal, Woutb, b_out, out, B_SZ, O_SZ, H_SZ);
}